// Round 1
// baseline (475.003 us; speedup 1.0000x reference)
//
#include <hip/hip_runtime.h>

// Problem constants (fixed by the reference): 131072 rows x 512 dims, 10 classes.
#define NROWS   131072
#define DIMS    512
#define NC      10
#define NCOPY   32           // striped atomic copies of the class sums
#define SUMSTRIDE 5120       // 10*512 floats per copy

typedef __attribute__((ext_vector_type(8))) short short8;   // 8 bf16 in 4 VGPRs
typedef __attribute__((ext_vector_type(4))) float floatx4;

// ---- helpers -------------------------------------------------------------

static __device__ __forceinline__ unsigned int pk2(float lo, float hi) {
    // pack two fp32 -> two bf16 (truncation; error irrelevant vs threshold)
    return (__float_as_uint(hi) & 0xFFFF0000u) | (__float_as_uint(lo) >> 16);
}

static __device__ __forceinline__ short8 pack8(const float4 a, const float4 b) {
    union { unsigned int u[4]; short8 v; } r;
    r.u[0] = pk2(a.x, a.y);
    r.u[1] = pk2(a.z, a.w);
    r.u[2] = pk2(b.x, b.y);
    r.u[3] = pk2(b.z, b.w);
    return r.v;
}

// ---- kernel 1: segment sums (per-class) + counts -------------------------
// 512 blocks x 256 threads. Thread (half = tid>>7, dt = tid&127) covers dims
// [4*dt, 4*dt+4) of rows rows0 + 2*i + half. Register accumulators, switch on
// wave-uniform label (scalar branches). Depth-2 prefetch hides HBM latency.

__global__ __launch_bounds__(256) void k_seg(const float* __restrict__ E,
                                             const int* __restrict__ L,
                                             float* __restrict__ sums,
                                             int* __restrict__ counts) {
    __shared__ float red[NC * DIMS];   // 20 KB merge buffer
    __shared__ int lc[16];
    const int tid  = threadIdx.x;
    const int half = tid >> 7;
    const int dt   = tid & 127;
    if (tid < 16) lc[tid] = 0;
    __syncthreads();

    const int rows0 = blockIdx.x * 256;
    const float4* Ev = (const float4*)E;

    float4 z = {0.f, 0.f, 0.f, 0.f};
    float4 a0=z,a1=z,a2=z,a3=z,a4=z,a5=z,a6=z,a7=z,a8=z,a9=z;

    int idx = (rows0 + half) * 128 + dt;
    float4 v = Ev[idx];
    int lab = L[rows0 + half];

    for (int i = 0; i < 128; ++i) {
        float4 vn = v; int ln = lab;
        if (i < 127) {                       // prefetch next row's data
            vn = Ev[idx + 256];
            ln = L[rows0 + 2 * i + 2 + half];
            idx += 256;
        }
        if (dt == 0) atomicAdd(&lc[lab], 1); // one count per (row,half=0/1)... see below
        switch (lab) {
            case 0: a0.x+=v.x; a0.y+=v.y; a0.z+=v.z; a0.w+=v.w; break;
            case 1: a1.x+=v.x; a1.y+=v.y; a1.z+=v.z; a1.w+=v.w; break;
            case 2: a2.x+=v.x; a2.y+=v.y; a2.z+=v.z; a2.w+=v.w; break;
            case 3: a3.x+=v.x; a3.y+=v.y; a3.z+=v.z; a3.w+=v.w; break;
            case 4: a4.x+=v.x; a4.y+=v.y; a4.z+=v.z; a4.w+=v.w; break;
            case 5: a5.x+=v.x; a5.y+=v.y; a5.z+=v.z; a5.w+=v.w; break;
            case 6: a6.x+=v.x; a6.y+=v.y; a6.z+=v.z; a6.w+=v.w; break;
            case 7: a7.x+=v.x; a7.y+=v.y; a7.z+=v.z; a7.w+=v.w; break;
            case 8: a8.x+=v.x; a8.y+=v.y; a8.z+=v.z; a8.w+=v.w; break;
            default: a9.x+=v.x; a9.y+=v.y; a9.z+=v.z; a9.w+=v.w; break;
        }
        v = vn; lab = ln;
    }
    // NOTE: threads dt==0 exist in half 0 (row 2i) and half 1 (row 2i+1):
    // every row counted exactly once.

    float4* R = (float4*)red;
    if (half) {
        R[0*128+dt]=a0; R[1*128+dt]=a1; R[2*128+dt]=a2; R[3*128+dt]=a3;
        R[4*128+dt]=a4; R[5*128+dt]=a5; R[6*128+dt]=a6; R[7*128+dt]=a7;
        R[8*128+dt]=a8; R[9*128+dt]=a9;
    }
    __syncthreads();
    if (!half) {
        const int base = (blockIdx.x & (NCOPY - 1)) * SUMSTRIDE;
        float4 t;
#define MERGE_ATOM(c, ac)                                                     \
        t = R[(c)*128 + dt];                                                  \
        ac.x += t.x; ac.y += t.y; ac.z += t.z; ac.w += t.w;                   \
        { float* d = &sums[base + (c)*512 + 4*dt];                            \
          atomicAdd(d+0, ac.x); atomicAdd(d+1, ac.y);                         \
          atomicAdd(d+2, ac.z); atomicAdd(d+3, ac.w); }
        MERGE_ATOM(0,a0) MERGE_ATOM(1,a1) MERGE_ATOM(2,a2) MERGE_ATOM(3,a3)
        MERGE_ATOM(4,a4) MERGE_ATOM(5,a5) MERGE_ATOM(6,a6) MERGE_ATOM(7,a7)
        MERGE_ATOM(8,a8) MERGE_ATOM(9,a9)
#undef MERGE_ATOM
    }
    if (tid < 16) {
        const int base = (blockIdx.x & (NCOPY - 1)) * 16;
        atomicAdd(&counts[base + tid], lc[tid]);
    }
}

// ---- kernel 2: reduce copies -> p2 = 2*prototype (fp32, [16][512] padded) -

__global__ __launch_bounds__(256) void k_proto(const float* __restrict__ sums,
                                               const int* __restrict__ counts,
                                               float* __restrict__ p2) {
    const int e = blockIdx.x * 256 + threadIdx.x;   // < 8192 = 16*512
    const int c = e >> 9;
    float val = 0.f;
    if (c < NC) {                                    // note: then e == c*512 + d < 5120
        float s = 0.f; int n = 0;
        for (int cp = 0; cp < NCOPY; ++cp) {
            s += sums[cp * SUMSTRIDE + e];
            n += counts[cp * 16 + c];
        }
        val = 2.f * s / (float)n;
    }
    p2[e] = val;
}

// ---- kernel 3: pn[c] = ||p_c||^2 (zero for padded classes) ---------------

__global__ __launch_bounds__(512) void k_pn(const float* __restrict__ p2,
                                            float* __restrict__ pn) {
    const int w = threadIdx.x >> 6, lane = threadIdx.x & 63;
    const float4* P = (const float4*)p2;
    for (int s = 0; s < 2; ++s) {
        const int c = w + s * 8;                    // covers 0..15
        float4 a = P[c * 128 + lane * 2];
        float4 b = P[c * 128 + lane * 2 + 1];
        float ss = a.x*a.x + a.y*a.y + a.z*a.z + a.w*a.w
                 + b.x*b.x + b.y*b.y + b.z*b.z + b.w*b.w;
        ss += __shfl_xor(ss, 1);  ss += __shfl_xor(ss, 2);
        ss += __shfl_xor(ss, 4);  ss += __shfl_xor(ss, 8);
        ss += __shfl_xor(ss, 16); ss += __shfl_xor(ss, 32);
        if (lane == 0) pn[c] = 0.25f * ss;          // p2 = 2p -> /4
    }
}

// ---- kernel 4: distances + logits + log-softmax + loss -------------------
// One wave per 16-row tile; MFMA 16x16x32 bf16 for the 2*e.p cross term.
// A-frag: lane holds row (lane&15), k = (lane>>4)*8 + j   [verified layout]
// C/D:    lane holds col (lane&15), rows (lane>>4)*4 + reg [verified layout]

__global__ __launch_bounds__(256) void k_main(const float* __restrict__ E,
                                              const int* __restrict__ L,
                                              const float* __restrict__ p2,
                                              const float* __restrict__ pn,
                                              float* __restrict__ out) {
    const int tid  = threadIdx.x;
    const int wid  = tid >> 6, lane = tid & 63;
    const int c16  = lane & 15, quad = lane >> 4;

    // B fragments (prototypes as bf16), built once per wave: 64 VGPRs
    short8 bf[16];
    const float4* P = (const float4*)p2;
#pragma unroll
    for (int kt = 0; kt < 16; ++kt) {
        float4 a = P[c16 * 128 + kt * 8 + quad * 2];
        float4 b = P[c16 * 128 + kt * 8 + quad * 2 + 1];
        bf[kt] = pack8(a, b);
    }
    const float pnc = pn[c16];

    float lossp = 0.f;
    const int gw = blockIdx.x * 4 + wid;            // 0..4095
    for (int t = gw; t < 8192; t += 4096) {
        const int tile  = 8191 - t;                 // reverse order: L3-friendly vs k_seg
        const int rbase = tile * 16;
        const float4* A = (const float4*)(E + (rbase + c16) * DIMS);

        floatx4 acc = {0.f, 0.f, 0.f, 0.f};
        float nrm = 0.f;
#pragma unroll
        for (int kt = 0; kt < 16; ++kt) {
            float4 a = A[kt * 8 + quad * 2];
            float4 b = A[kt * 8 + quad * 2 + 1];
            nrm += a.x*a.x + a.y*a.y + a.z*a.z + a.w*a.w;
            nrm += b.x*b.x + b.y*b.y + b.z*b.z + b.w*b.w;
            acc = __builtin_amdgcn_mfma_f32_16x16x32_bf16(pack8(a, b), bf[kt],
                                                          acc, 0, 0, 0);
        }
        // full ||e_row||^2 for row (lane&15): sum the 4 k-phases
        nrm += __shfl_xor(nrm, 16);
        nrm += __shfl_xor(nrm, 32);

#pragma unroll
        for (int i = 0; i < 4; ++i) {
            const int row = rbase + quad * 4 + i;
            const float nr = __shfl(nrm, quad * 4 + i);   // lane r holds norm of row r (r<16)
            float lg = acc[i] - nr - pnc;                  // = 2e.p - ||e||^2 - ||p||^2 = -d2
            lg = fminf(lg, 0.f);                           // reference clamps d2 >= 0
            float ml = (c16 < NC) ? lg : -3.0e38f;
            ml = fmaxf(ml, __shfl_xor(ml, 1));
            ml = fmaxf(ml, __shfl_xor(ml, 2));
            ml = fmaxf(ml, __shfl_xor(ml, 4));
            ml = fmaxf(ml, __shfl_xor(ml, 8));
            float ex = (c16 < NC) ? __expf(lg - ml) : 0.f;
            ex += __shfl_xor(ex, 1);
            ex += __shfl_xor(ex, 2);
            ex += __shfl_xor(ex, 4);
            ex += __shfl_xor(ex, 8);
            const float lse = ml + __logf(ex);
            if (c16 < NC) out[1 + row * NC + c16] = lg;
            const int lab = L[row];
            if (c16 == lab) lossp += lse - lg;
        }
    }

    lossp += __shfl_xor(lossp, 1);  lossp += __shfl_xor(lossp, 2);
    lossp += __shfl_xor(lossp, 4);  lossp += __shfl_xor(lossp, 8);
    lossp += __shfl_xor(lossp, 16); lossp += __shfl_xor(lossp, 32);
    __shared__ float ls[4];
    if (lane == 0) ls[wid] = lossp;
    __syncthreads();
    if (tid == 0)
        atomicAdd(out, (ls[0] + ls[1] + ls[2] + ls[3]) * (1.0f / (float)NROWS));
}

// ---- launch --------------------------------------------------------------

extern "C" void kernel_launch(void* const* d_in, const int* in_sizes, int n_in,
                              void* d_out, int out_size, void* d_ws, size_t ws_size,
                              hipStream_t stream) {
    const float* E = (const float*)d_in[0];
    const int*   L = (const int*)d_in[1];
    float* out = (float*)d_out;
    char* ws = (char*)d_ws;

    // ws layout (bytes): sums 32*5120*4 = 655360 | counts 32*16*4 = 2048 |
    //                    p2 16*512*4 = 32768     | pn 16*4
    float* sums   = (float*)ws;
    int*   counts = (int*)(ws + 655360);
    float* p2     = (float*)(ws + 657408);
    float* pn     = (float*)(ws + 690176);

    (void)hipMemsetAsync(d_ws, 0, 657408, stream);         // zero sums + counts
    (void)hipMemsetAsync(d_out, 0, sizeof(float), stream); // zero loss accumulator

    k_seg  <<<NROWS / 256, 256, 0, stream>>>(E, L, sums, counts);
    k_proto<<<32,          256, 0, stream>>>(sums, counts, p2);
    k_pn   <<<1,           512, 0, stream>>>(p2, pn);
    k_main <<<1024,        256, 0, stream>>>(E, L, p2, pn, out);
}